// Round 6
// baseline (563.928 us; speedup 1.0000x reference)
//
#include <hip/hip_runtime.h>

#define NPTS 512
#define DIM  256
#define HID  128
#define NSEG 64
#define LN_EPS 1e-5f

typedef short s16x4 __attribute__((ext_vector_type(4)));
typedef short s16x8 __attribute__((ext_vector_type(8)));
typedef float f32x4 __attribute__((ext_vector_type(4)));
typedef const float* fpc;

__device__ __forceinline__ unsigned short f2bf(float f) {
  unsigned int u = __builtin_bit_cast(unsigned int, f);
  u += 0x7FFFu + ((u >> 16) & 1u);
  return (unsigned short)(u >> 16);
}

// ---------------- K1 v2: pairwise geo features -> MLP -> mean over j --------------------
// Per block (one i): startup precomputes x[9] + LN1 stats (via w1-quadform) for all 512 j
// into LDS; phase A is then pure FMA (no shuffles, no sqrt); Linear2 MFMA + LN2 unchanged
// from the proven round-4 kernel.
__global__ __launch_bounds__(256, 4) void k1_geo(
    fpc coords, fpc w1, fpc b1, fpc g1, fpc be1,
    fpc w2, fpc b2, fpc g2, fpc be2,
    float* __restrict__ geo_ctx)
{
  const int t = threadIdx.x;
  const int lane = t & 63;
  const int wid = t >> 6;
  const int bi = blockIdx.x;           // b*512 + i
  const int b = bi >> 9;

  __shared__ __align__(16) float xs[NPTS][12];           // 24KB  x features (x4,x5 = 0)
  __shared__ __align__(16) float st[NPTS][2];            // 4KB   {mean, rstd} of LN1 pre-act
  __shared__ __align__(16) float qf[128];                // Q[9][12] @0, cw@108, tv@117, cb@126, sb2@127
  __shared__ __align__(16) unsigned short h1s[16][136];  // 4.25KB
  __shared__ __align__(16) float red2[16][8];

  // ---- startup A: quadform constants from w1/b1 (cooperative, one job per thread)
  if (t < 101) {
    float acc = 0.f;
    if (t < 81) {
      const int a = t / 9, c = t % 9;
      for (int h = 0; h < HID; ++h) acc += w1[h * 9 + a] * w1[h * 9 + c];
      qf[a * 12 + c] = acc;
    } else if (t < 90) {
      const int a = t - 81;
      for (int h = 0; h < HID; ++h) acc += w1[h * 9 + a];
      qf[108 + a] = acc;
    } else if (t < 99) {
      const int a = t - 90;
      for (int h = 0; h < HID; ++h) acc += b1[h] * w1[h * 9 + a];
      qf[117 + a] = acc;
    } else if (t == 99) {
      for (int h = 0; h < HID; ++h) acc += b1[h];
      qf[126] = acc;
    } else {
      for (int h = 0; h < HID; ++h) acc += b1[h] * b1[h];
      qf[127] = acc;
    }
  }
  // ---- per-thread weight registers (phase A channels; unchanged from proven kernel)
  const int u  = lane & 31;
  const int hw = lane >> 5;
  const int h0 = u * 4;
  float w1r[4][9], b1r[4], g1r[4], be1r[4];
  #pragma unroll
  for (int r = 0; r < 4; ++r) {
    #pragma unroll
    for (int k = 0; k < 9; ++k) w1r[r][k] = w1[(h0 + r) * 9 + k];
    b1r[r] = b1[h0 + r]; g1r[r] = g1[h0 + r]; be1r[r] = be1[h0 + r];
  }
  const int n16 = lane & 15;
  const int q16 = lane >> 4;
  s16x8 bfrag[4][4];
  float b2r[4], g2r[4], be2r[4];
  #pragma unroll
  for (int dt = 0; dt < 4; ++dt) {
    const int d = (wid * 4 + dt) * 16 + n16;
    b2r[dt] = b2[d]; g2r[dt] = g2[d]; be2r[dt] = be2[d];
    #pragma unroll
    for (int kt = 0; kt < 4; ++kt) {
      const int kb = kt * 32 + q16 * 8;
      s16x8 f;
      #pragma unroll
      for (int jj = 0; jj < 8; ++jj) f[jj] = (short)f2bf(w2[d * HID + kb + jj]);
      bfrag[dt][kt] = f;
    }
  }
  const float cix = coords[bi * 3 + 0];
  const float ciy = coords[bi * 3 + 1];
  const float ciz = coords[bi * 3 + 2];
  __syncthreads();

  // ---- startup B: x + LN1 stats for all 512 j (2 per thread)
  #pragma unroll
  for (int jj = 0; jj < 2; ++jj) {
    const int j = t + jj * 256;
    const float cjx = coords[(b * NPTS + j) * 3 + 0];
    const float cjy = coords[(b * NPTS + j) * 3 + 1];
    const float cjz = coords[(b * NPTS + j) * 3 + 2];
    const float rx = cix - cjx, ry = ciy - cjy, rz = ciz - cjz;
    const float dist = sqrtf(rx * rx + ry * ry + rz * rz);
    const float inv = 1.f / fmaxf(dist, 1e-12f);
    const float r0 = rx * inv, r1 = ry * inv, r2 = rz * inv;
    const float x0 = dist, x1 = r0, x2 = r1, x3 = r2;
    const float x6 = r1 * r2, x7 = r0 * r1, x8 = r0 * r2;
    // S1 = cb + cw.x ; tx = tv.x ; quad = x^T Q x   (x4=x5=0)
    float S1 = qf[126] + qf[108] * x0 + qf[109] * x1 + qf[110] * x2 + qf[111] * x3
             + qf[114] * x6 + qf[115] * x7 + qf[116] * x8;
    float tx = qf[117] * x0 + qf[118] * x1 + qf[119] * x2 + qf[120] * x3
             + qf[123] * x6 + qf[124] * x7 + qf[125] * x8;
    const float xv[9] = {x0, x1, x2, x3, 0.f, 0.f, x6, x7, x8};
    float quad = 0.f;
    #pragma unroll
    for (int a = 0; a < 9; ++a) {
      if (a == 4 || a == 5) continue;
      const f32x4 q0 = *(const f32x4*)&qf[a * 12];
      const f32x4 q1 = *(const f32x4*)&qf[a * 12 + 4];
      const f32x4 q2 = *(const f32x4*)&qf[a * 12 + 8];
      const float ya = q0[0] * x0 + q0[1] * x1 + q0[2] * x2 + q0[3] * x3
                     + q1[2] * x6 + q1[3] * x7 + q2[0] * x8;
      quad += ya * xv[a];
    }
    const float S2 = quad + 2.f * tx + qf[127];
    const float mean = S1 * (1.f / 128.f);
    const float var = fmaxf(S2 * (1.f / 128.f) - mean * mean, 0.f);
    st[j][0] = mean;
    st[j][1] = rsqrtf(var + LN_EPS);
    f32x4 X0; X0[0] = x0; X0[1] = x1; X0[2] = x2; X0[3] = x3;
    f32x4 X1; X1[0] = 0.f; X1[1] = 0.f; X1[2] = x6; X1[3] = x7;
    f32x4 X2; X2[0] = x8; X2[1] = 0.f; X2[2] = 0.f; X2[3] = 0.f;
    *(f32x4*)&xs[j][0] = X0;
    *(f32x4*)&xs[j][4] = X1;
    *(f32x4*)&xs[j][8] = X2;
  }
  __syncthreads();

  float accg[4] = {0.f, 0.f, 0.f, 0.f};

  for (int jb = 0; jb < NPTS; jb += 16) {
    // ---- phase A: h1 = ReLU(LN1(x@w1^T + b1)) -> bf16 LDS (no cross-lane ops)
    #pragma unroll
    for (int sr = 0; sr < 2; ++sr) {
      const int m = sr * 8 + wid * 2 + hw;
      const int j = jb + m;
      const f32x4 X0 = *(const f32x4*)&xs[j][0];
      const f32x4 X1 = *(const f32x4*)&xs[j][4];
      const f32x4 X2 = *(const f32x4*)&xs[j][8];
      const float2 ms = *(const float2*)&st[j][0];
      s16x4 hn;
      #pragma unroll
      for (int r = 0; r < 4; ++r) {
        const float a = b1r[r]
          + X0[0] * w1r[r][0] + X0[1] * w1r[r][1] + X0[2] * w1r[r][2] + X0[3] * w1r[r][3]
          + X1[2] * w1r[r][6] + X1[3] * w1r[r][7] + X2[0] * w1r[r][8];
        const float e = (a - ms.x) * ms.y * g1r[r] + be1r[r];
        hn[r] = (short)f2bf(fmaxf(e, 0.f));
      }
      *(s16x4*)&h1s[m][h0] = hn;
    }
    __syncthreads();
    // ---- phase B: MFMA (unchanged)
    s16x8 af[4];
    #pragma unroll
    for (int kt = 0; kt < 4; ++kt)
      af[kt] = *(const s16x8*)&h1s[n16][kt * 32 + q16 * 8];
    f32x4 acc[4];
    #pragma unroll
    for (int dt = 0; dt < 4; ++dt) {
      f32x4 a = {0.f, 0.f, 0.f, 0.f};
      #pragma unroll
      for (int kt = 0; kt < 4; ++kt)
        a = __builtin_amdgcn_mfma_f32_16x16x32_bf16(af[kt], bfrag[dt][kt], a, 0, 0, 0);
      acc[dt] = a;
    }
    // ---- LN2 (unchanged)
    float sR[4], qR[4];
    #pragma unroll
    for (int r = 0; r < 4; ++r) {
      float s = 0.f, q = 0.f;
      #pragma unroll
      for (int dt = 0; dt < 4; ++dt) {
        const float v = acc[dt][r] + b2r[dt];
        s += v; q += v * v;
      }
      sR[r] = s; qR[r] = q;
    }
    #pragma unroll
    for (int off = 1; off < 16; off <<= 1) {
      #pragma unroll
      for (int r = 0; r < 4; ++r) {
        sR[r] += __shfl_xor(sR[r], off);
        qR[r] += __shfl_xor(qR[r], off);
      }
    }
    if (n16 == 0) {
      #pragma unroll
      for (int r = 0; r < 4; ++r) {
        red2[q16 * 4 + r][wid * 2 + 0] = sR[r];
        red2[q16 * 4 + r][wid * 2 + 1] = qR[r];
      }
    }
    __syncthreads();
    #pragma unroll
    for (int r = 0; r < 4; ++r) {
      const int row = q16 * 4 + r;
      const f32x4 p0 = *(const f32x4*)&red2[row][0];
      const f32x4 p1 = *(const f32x4*)&red2[row][4];
      const float s = p0[0] + p0[2] + p1[0] + p1[2];
      const float q = p0[1] + p0[3] + p1[1] + p1[3];
      const float mean = s * (1.f / 256.f);
      const float var = fmaxf(q * (1.f / 256.f) - mean * mean, 0.f);
      const float rs = rsqrtf(var + LN_EPS);
      #pragma unroll
      for (int dt = 0; dt < 4; ++dt) {
        const float v = acc[dt][r] + b2r[dt];
        accg[dt] += (v - mean) * rs * g2r[dt] + be2r[dt];
      }
    }
    __syncthreads();
  }
  #pragma unroll
  for (int dt = 0; dt < 4; ++dt) {
    float v = accg[dt];
    v += __shfl_xor(v, 16);
    v += __shfl_xor(v, 32);
    if (lane < 16) geo_ctx[bi * DIM + (wid * 4 + dt) * 16 + lane] = v * (1.f / 512.f);
  }
}

// ---------------- K2: per-(b,s) segment means + aggregator MLP -> comb, cnt -------------
__global__ void k2_agg(
    fpc features, const int* __restrict__ labels, const float* __restrict__ geo_ctx,
    fpc w1, fpc b1, fpc g1, fpc be1, fpc w2, fpc b2, fpc g2, fpc be2,
    float* __restrict__ comb, float* __restrict__ cntf)
{
  const int t = threadIdx.x;
  const int lane = t & 63;
  const int wid = t >> 6;
  const int b = blockIdx.x >> 6;
  const int s = blockIdx.x & 63;
  __shared__ __align__(16) int labS[NPTS];
  __shared__ __align__(16) float mfS[DIM];
  __shared__ __align__(16) float h1S[HID];
  __shared__ __align__(16) float red[8];
  for (int n = t; n < NPTS; n += 256) labS[n] = labels[b * NPTS + n];
  __syncthreads();
  float accf = 0.f, accgv = 0.f;
  int cnt = 0;
  for (int n = 0; n < NPTS; n += 4) {        // batched label reads (one b128)
    const int4 l4 = *(const int4*)&labS[n];
    if (l4.x == s) { cnt++; accf += features[(b * NPTS + n + 0) * DIM + t]; accgv += geo_ctx[(b * NPTS + n + 0) * DIM + t]; }
    if (l4.y == s) { cnt++; accf += features[(b * NPTS + n + 1) * DIM + t]; accgv += geo_ctx[(b * NPTS + n + 1) * DIM + t]; }
    if (l4.z == s) { cnt++; accf += features[(b * NPTS + n + 2) * DIM + t]; accgv += geo_ctx[(b * NPTS + n + 2) * DIM + t]; }
    if (l4.w == s) { cnt++; accf += features[(b * NPTS + n + 3) * DIM + t]; accgv += geo_ctx[(b * NPTS + n + 3) * DIM + t]; }
  }
  const float denom = fmaxf((float)cnt, 1.f);
  const float mfd = accf / denom, mgd = accgv / denom;
  mfS[t] = mfd;
  __syncthreads();
  float hval = 0.f;
  if (t < HID) {
    float o = b1[t];
    for (int k = 0; k < DIM; k += 4) {
      const f32x4 x = *(const f32x4*)&mfS[k];
      const f32x4 w = *(const f32x4*)&w1[t * DIM + k];
      o += x[0] * w[0] + x[1] * w[1] + x[2] * w[2] + x[3] * w[3];
    }
    hval = o;
  }
  float sv = (t < HID) ? hval : 0.f;
  float qv = (t < HID) ? hval * hval : 0.f;
  #pragma unroll
  for (int off = 1; off < 64; off <<= 1) { sv += __shfl_xor(sv, off); qv += __shfl_xor(qv, off); }
  if (lane == 0 && wid < 2) { red[wid * 2] = sv; red[wid * 2 + 1] = qv; }
  __syncthreads();
  if (t < HID) {
    const float s1 = red[0] + red[2], q1 = red[1] + red[3];
    const float mean = s1 * (1.f / 128.f);
    const float var = fmaxf(q1 * (1.f / 128.f) - mean * mean, 0.f);
    const float rs = rsqrtf(var + LN_EPS);
    h1S[t] = fmaxf((hval - mean) * rs * g1[t] + be1[t], 0.f);
  }
  __syncthreads();
  float o = b2[t];
  for (int k = 0; k < HID; k += 4) {
    const f32x4 x = *(const f32x4*)&h1S[k];
    const f32x4 w = *(const f32x4*)&w2[t * HID + k];
    o += x[0] * w[0] + x[1] * w[1] + x[2] * w[2] + x[3] * w[3];
  }
  float sv2 = o, qv2 = o * o;
  #pragma unroll
  for (int off = 1; off < 64; off <<= 1) { sv2 += __shfl_xor(sv2, off); qv2 += __shfl_xor(qv2, off); }
  if (lane == 0) { red[wid * 2] = sv2; red[wid * 2 + 1] = qv2; }
  __syncthreads();
  const float sa = red[0] + red[2] + red[4] + red[6];
  const float qa = red[1] + red[3] + red[5] + red[7];
  const float mean = sa * (1.f / 256.f);
  const float var = fmaxf(qa * (1.f / 256.f) - mean * mean, 0.f);
  const float rs = rsqrtf(var + LN_EPS);
  const float e = (o - mean) * rs * g2[t] + be2[t];
  comb[(b * NSEG + s) * DIM + t] = e + mgd;
  if (t == 0) cntf[b * NSEG + s] = (float)cnt;
}

// ---------------- K4: Q/K/V projections (round-4 tiling, enh fused at staging) ----------
__global__ __launch_bounds__(256) void k4_qkv(
    fpc features, const int* __restrict__ labels,
    const float* __restrict__ comb, const float* __restrict__ cntf,
    const float* __restrict__ geo_ctx,
    fpc wq, fpc bq, fpc wk, fpc bk, fpc wv, fpc bv,
    float* __restrict__ Q, float* __restrict__ Ko, float* __restrict__ V,
    float* __restrict__ enh)
{
  const int blk = blockIdx.x;
  const int proj = blk >> 6;
  const int rem = blk & 63;
  const int b = rem >> 5;
  const int nt = rem & 31;
  const int n0 = b * NPTS + nt * 16;
  fpc W = (proj == 0) ? wq : (proj == 1 ? wk : wv);
  fpc bias = (proj == 0) ? bq : (proj == 1 ? bk : bv);
  float* out = (proj == 0) ? Q : (proj == 1 ? Ko : V);
  __shared__ __align__(16) float Xs[16][256];
  const int t = threadIdx.x;
  for (int idx = t * 4; idx < 16 * 256; idx += 1024) {
    const int r = idx >> 8, c = idx & 255;
    const int row = n0 + r;
    f32x4 v;
    if (proj == 0) {
      const int l = labels[row];
      const float cn = cntf[b * NSEG + l];
      const f32x4 f = *(const f32x4*)&features[row * DIM + c];
      if (cn >= 2.f) {
        const f32x4 cb = *(const f32x4*)&comb[(b * NSEG + l) * DIM + c];
        #pragma unroll
        for (int i = 0; i < 4; ++i) v[i] = 0.7f * f[i] + 0.3f * cb[i];
      } else {
        v = f;
      }
      *(f32x4*)&enh[row * DIM + c] = v;    // exactly one proj0 block per (b,nt)
    } else {
      v = *(const f32x4*)&geo_ctx[row * DIM + c];
    }
    *(f32x4*)&Xs[r][c] = v;
  }
  __syncthreads();
  const int r0 = (t >> 6) * 4;
  const int c0 = (t & 63) * 4;
  float acc[4][4] = {};
  for (int k = 0; k < DIM; k += 4) {
    f32x4 xq[4];
    #pragma unroll
    for (int r = 0; r < 4; ++r) xq[r] = *(const f32x4*)&Xs[r0 + r][k];
    f32x4 wf[4];
    #pragma unroll
    for (int c = 0; c < 4; ++c) wf[c] = *(const f32x4*)&W[(c0 + c) * DIM + k];
    #pragma unroll
    for (int r = 0; r < 4; ++r)
      #pragma unroll
      for (int c = 0; c < 4; ++c)
        acc[r][c] += xq[r][0] * wf[c][0] + xq[r][1] * wf[c][1]
                   + xq[r][2] * wf[c][2] + xq[r][3] * wf[c][3];
  }
  #pragma unroll
  for (int r = 0; r < 4; ++r) {
    f32x4 o;
    #pragma unroll
    for (int c = 0; c < 4; ++c) o[c] = acc[r][c] + bias[c0 + c];
    *(f32x4*)&out[(n0 + r0 + r) * DIM + c0] = o;
  }
}

// ---------------- K5: attention per (b, head, 16-q-row tile) — round-4 form -------------
__global__ void k5_attn(const float* __restrict__ Q, const float* __restrict__ Kv,
                        const float* __restrict__ V, float* __restrict__ O)
{
  const int blk = blockIdx.x;
  const int qt = blk & 31;
  const int h = (blk >> 5) & 7;
  const int b = blk >> 8;
  const int t = threadIdx.x;
  __shared__ __align__(16) float Sx[16][516];
  __shared__ __align__(16) float rinv[16];
  {
    const int r = t & 15, kc = t >> 4;
    const int qrow = b * NPTS + qt * 16 + r;
    f32x4 qv[8];
    #pragma unroll
    for (int i = 0; i < 8; ++i) qv[i] = *(const f32x4*)&Q[qrow * DIM + h * 32 + i * 4];
    for (int kk = 0; kk < 32; ++kk) {
      const int krow = b * NPTS + kc * 32 + kk;
      const f32x4* kp = (const f32x4*)&Kv[krow * DIM + h * 32];
      float sd = 0.f;
      #pragma unroll
      for (int i = 0; i < 8; ++i) {
        const f32x4 kvv = kp[i];
        sd += qv[i][0] * kvv[0] + qv[i][1] * kvv[1] + qv[i][2] * kvv[2] + qv[i][3] * kvv[3];
      }
      Sx[r][kc * 32 + kk] = sd * 0.1767766952966369f;   // 1/sqrt(32)
    }
  }
  __syncthreads();
  {
    const int r2 = t >> 4, cl = t & 15;
    float mx = -3.4e38f;
    for (int i = 0; i < 32; ++i) mx = fmaxf(mx, Sx[r2][cl + 16 * i]);
    #pragma unroll
    for (int off = 1; off < 16; off <<= 1) mx = fmaxf(mx, __shfl_xor(mx, off));
    float sm = 0.f;
    for (int i = 0; i < 32; ++i) {
      const float e = __expf(Sx[r2][cl + 16 * i] - mx);
      Sx[r2][cl + 16 * i] = e;
      sm += e;
    }
    #pragma unroll
    for (int off = 1; off < 16; off <<= 1) sm += __shfl_xor(sm, off);
    if (cl == 0) rinv[r2] = 1.f / sm;
  }
  __syncthreads();
  {
    const int r3 = t >> 4;
    const int e0 = (t & 15) * 2;
    float o0 = 0.f, o1 = 0.f;
    for (int k = 0; k < NPTS; ++k) {
      const float p = Sx[r3][k];
      const float2 vv = *(const float2*)&V[(b * NPTS + k) * DIM + h * 32 + e0];
      o0 += p * vv.x; o1 += p * vv.y;
    }
    const float ri = rinv[r3];
    float2 ov; ov.x = o0 * ri; ov.y = o1 * ri;
    *(float2*)&O[(b * NPTS + qt * 16 + r3) * DIM + h * 32 + e0] = ov;
  }
}

// ---------------- K6: out = enh + 0.5*(O @ wo^T + bo) — round-4 form --------------------
__global__ void k6_out(const float* __restrict__ O, const float* __restrict__ enh,
                       fpc wo, fpc bo, float* __restrict__ out)
{
  const int blk = blockIdx.x;          // b*64 + 8-row tile
  const int b = blk >> 6;
  const int nt = blk & 63;
  const int n0 = b * NPTS + nt * 8;
  const int t = threadIdx.x;
  __shared__ __align__(16) float Xs[8][256];
  for (int idx = t * 4; idx < 8 * 256; idx += 1024) {
    const int r = idx >> 8, c = idx & 255;
    *(f32x4*)&Xs[r][c] = *(const f32x4*)&O[(n0 + r) * DIM + c];
  }
  __syncthreads();
  const int r0 = (t >> 6) * 2;
  const int c0 = (t & 63) * 4;
  float acc[2][4] = {};
  for (int k = 0; k < DIM; k += 4) {
    f32x4 xq[2];
    xq[0] = *(const f32x4*)&Xs[r0][k];
    xq[1] = *(const f32x4*)&Xs[r0 + 1][k];
    #pragma unroll
    for (int c = 0; c < 4; ++c) {
      const f32x4 w = *(const f32x4*)&wo[(c0 + c) * DIM + k];
      #pragma unroll
      for (int r = 0; r < 2; ++r)
        acc[r][c] += xq[r][0] * w[0] + xq[r][1] * w[1] + xq[r][2] * w[2] + xq[r][3] * w[3];
    }
  }
  #pragma unroll
  for (int r = 0; r < 2; ++r) {
    const int row = n0 + r0 + r;
    const f32x4 ev = *(const f32x4*)&enh[row * DIM + c0];
    f32x4 o;
    #pragma unroll
    for (int c = 0; c < 4; ++c)
      o[c] = ev[c] + 0.5f * (acc[r][c] + bo[c0 + c]);
    *(f32x4*)&out[row * DIM + c0] = o;
  }
}

extern "C" void kernel_launch(void* const* d_in, const int* in_sizes, int n_in,
                              void* d_out, int out_size, void* d_ws, size_t ws_size,
                              hipStream_t stream)
{
  fpc coords  = (fpc)d_in[0];
  fpc features= (fpc)d_in[1];
  const int* labels = (const int*)d_in[2];
  fpc ge_w1 = (fpc)d_in[3],  ge_b1 = (fpc)d_in[4],  ge_g1 = (fpc)d_in[5],  ge_be1 = (fpc)d_in[6];
  fpc ge_w2 = (fpc)d_in[7],  ge_b2 = (fpc)d_in[8],  ge_g2 = (fpc)d_in[9],  ge_be2 = (fpc)d_in[10];
  fpc ag_w1 = (fpc)d_in[11], ag_b1 = (fpc)d_in[12], ag_g1 = (fpc)d_in[13], ag_be1 = (fpc)d_in[14];
  fpc ag_w2 = (fpc)d_in[15], ag_b2 = (fpc)d_in[16], ag_g2 = (fpc)d_in[17], ag_be2 = (fpc)d_in[18];
  fpc wq = (fpc)d_in[19], bq = (fpc)d_in[20];
  fpc wk = (fpc)d_in[21], bk = (fpc)d_in[22];
  fpc wv = (fpc)d_in[23], bv = (fpc)d_in[24];
  fpc wo = (fpc)d_in[25], bo = (fpc)d_in[26];

  float* ws = (float*)d_ws;
  float* geo_ctx = ws;                    // 262144
  float* comb    = geo_ctx + 262144;      // 32768
  float* cntf    = comb + 32768;          // 128
  float* enh     = cntf + 128;            // 262144
  float* Qb      = enh + 262144;          // 262144
  float* Kb      = Qb + 262144;           // 262144
  float* Vb      = Kb + 262144;           // 262144
  float* Ob      = Vb + 262144;           // 262144

  k1_geo<<<1024, 256, 0, stream>>>(coords, ge_w1, ge_b1, ge_g1, ge_be1,
                                   ge_w2, ge_b2, ge_g2, ge_be2, geo_ctx);
  k2_agg<<<128, 256, 0, stream>>>(features, labels, geo_ctx,
                                  ag_w1, ag_b1, ag_g1, ag_be1,
                                  ag_w2, ag_b2, ag_g2, ag_be2, comb, cntf);
  k4_qkv<<<192, 256, 0, stream>>>(features, labels, comb, cntf, geo_ctx,
                                  wq, bq, wk, bk, wv, bv, Qb, Kb, Vb, enh);
  k5_attn<<<512, 256, 0, stream>>>(Qb, Kb, Vb, Ob);
  k6_out<<<128, 256, 0, stream>>>(Ob, enh, wo, bo, (float*)d_out);
}

// Round 7
// 415.302 us; speedup vs baseline: 1.3579x; 1.3579x over previous
//
#include <hip/hip_runtime.h>

#define NPTS 512
#define DIM  256
#define HID  128
#define NSEG 64
#define LN_EPS 1e-5f

typedef short s16x4 __attribute__((ext_vector_type(4)));
typedef short s16x8 __attribute__((ext_vector_type(8)));
typedef float f32x4 __attribute__((ext_vector_type(4)));
typedef const float* fpc;

__device__ __forceinline__ unsigned short f2bf(float f) {
  unsigned int u = __builtin_bit_cast(unsigned int, f);
  u += 0x7FFFu + ((u >> 16) & 1u);
  return (unsigned short)(u >> 16);
}

// ---------------- K1 v2b: pairwise geo features -> MLP -> mean over j -------------------
// Startup precomputes x[9] + LN1 stats (w1-quadform) for all 512 j into LDS; phase A is
// pure FMA (no shuffles/sqrt). launch_bounds (256,2): round-6's (256,4) capped VGPR at 64
// and spilled bfrag/w1r to scratch (FETCH 918 MB, k1 330us). Cap 256 -> no spill.
__global__ __launch_bounds__(256, 2) void k1_geo(
    fpc coords, fpc w1, fpc b1, fpc g1, fpc be1,
    fpc w2, fpc b2, fpc g2, fpc be2,
    float* __restrict__ geo_ctx)
{
  const int t = threadIdx.x;
  const int lane = t & 63;
  const int wid = t >> 6;
  const int bi = blockIdx.x;           // b*512 + i
  const int b = bi >> 9;

  __shared__ __align__(16) float xs[NPTS][12];           // 24KB  x features (x4,x5 = 0)
  __shared__ __align__(16) float st[NPTS][2];            // 4KB   {mean, rstd} of LN1 pre-act
  __shared__ __align__(16) float qf[128];                // Q[9][12] @0, cw@108, tv@117, cb@126, sb2@127
  __shared__ __align__(16) unsigned short h1s[16][136];  // 4.25KB
  __shared__ __align__(16) float red2[16][8];

  // ---- startup A: quadform constants from w1/b1 (cooperative, one job per thread)
  if (t < 101) {
    float acc = 0.f;
    if (t < 81) {
      const int a = t / 9, c = t % 9;
      for (int h = 0; h < HID; ++h) acc += w1[h * 9 + a] * w1[h * 9 + c];
      qf[a * 12 + c] = acc;
    } else if (t < 90) {
      const int a = t - 81;
      for (int h = 0; h < HID; ++h) acc += w1[h * 9 + a];
      qf[108 + a] = acc;
    } else if (t < 99) {
      const int a = t - 90;
      for (int h = 0; h < HID; ++h) acc += b1[h] * w1[h * 9 + a];
      qf[117 + a] = acc;
    } else if (t == 99) {
      for (int h = 0; h < HID; ++h) acc += b1[h];
      qf[126] = acc;
    } else {
      for (int h = 0; h < HID; ++h) acc += b1[h] * b1[h];
      qf[127] = acc;
    }
  }
  // ---- per-thread weight registers (phase A channels)
  const int u  = lane & 31;
  const int hw = lane >> 5;
  const int h0 = u * 4;
  float w1r[4][9], b1r[4], g1r[4], be1r[4];
  #pragma unroll
  for (int r = 0; r < 4; ++r) {
    #pragma unroll
    for (int k = 0; k < 9; ++k) w1r[r][k] = w1[(h0 + r) * 9 + k];
    b1r[r] = b1[h0 + r]; g1r[r] = g1[h0 + r]; be1r[r] = be1[h0 + r];
  }
  const int n16 = lane & 15;
  const int q16 = lane >> 4;
  s16x8 bfrag[4][4];
  float b2r[4], g2r[4], be2r[4];
  #pragma unroll
  for (int dt = 0; dt < 4; ++dt) {
    const int d = (wid * 4 + dt) * 16 + n16;
    b2r[dt] = b2[d]; g2r[dt] = g2[d]; be2r[dt] = be2[d];
    #pragma unroll
    for (int kt = 0; kt < 4; ++kt) {
      const int kb = kt * 32 + q16 * 8;
      s16x8 f;
      #pragma unroll
      for (int jj = 0; jj < 8; ++jj) f[jj] = (short)f2bf(w2[d * HID + kb + jj]);
      bfrag[dt][kt] = f;
    }
  }
  const float cix = coords[bi * 3 + 0];
  const float ciy = coords[bi * 3 + 1];
  const float ciz = coords[bi * 3 + 2];
  __syncthreads();

  // ---- startup B: x + LN1 stats for all 512 j (2 per thread)
  #pragma unroll
  for (int jj = 0; jj < 2; ++jj) {
    const int j = t + jj * 256;
    const float cjx = coords[(b * NPTS + j) * 3 + 0];
    const float cjy = coords[(b * NPTS + j) * 3 + 1];
    const float cjz = coords[(b * NPTS + j) * 3 + 2];
    const float rx = cix - cjx, ry = ciy - cjy, rz = ciz - cjz;
    const float dist = sqrtf(rx * rx + ry * ry + rz * rz);
    const float inv = 1.f / fmaxf(dist, 1e-12f);
    const float r0 = rx * inv, r1 = ry * inv, r2 = rz * inv;
    const float x0 = dist, x1 = r0, x2 = r1, x3 = r2;
    const float x6 = r1 * r2, x7 = r0 * r1, x8 = r0 * r2;
    float S1 = qf[126] + qf[108] * x0 + qf[109] * x1 + qf[110] * x2 + qf[111] * x3
             + qf[114] * x6 + qf[115] * x7 + qf[116] * x8;
    float tx = qf[117] * x0 + qf[118] * x1 + qf[119] * x2 + qf[120] * x3
             + qf[123] * x6 + qf[124] * x7 + qf[125] * x8;
    const float xv[9] = {x0, x1, x2, x3, 0.f, 0.f, x6, x7, x8};
    float quad = 0.f;
    #pragma unroll
    for (int a = 0; a < 9; ++a) {
      if (a == 4 || a == 5) continue;
      const f32x4 q0 = *(const f32x4*)&qf[a * 12];
      const f32x4 q1 = *(const f32x4*)&qf[a * 12 + 4];
      const f32x4 q2 = *(const f32x4*)&qf[a * 12 + 8];
      const float ya = q0[0] * x0 + q0[1] * x1 + q0[2] * x2 + q0[3] * x3
                     + q1[2] * x6 + q1[3] * x7 + q2[0] * x8;
      quad += ya * xv[a];
    }
    const float S2 = quad + 2.f * tx + qf[127];
    const float mean = S1 * (1.f / 128.f);
    const float var = fmaxf(S2 * (1.f / 128.f) - mean * mean, 0.f);
    st[j][0] = mean;
    st[j][1] = rsqrtf(var + LN_EPS);
    f32x4 X0; X0[0] = x0; X0[1] = x1; X0[2] = x2; X0[3] = x3;
    f32x4 X1; X1[0] = 0.f; X1[1] = 0.f; X1[2] = x6; X1[3] = x7;
    f32x4 X2; X2[0] = x8; X2[1] = 0.f; X2[2] = 0.f; X2[3] = 0.f;
    *(f32x4*)&xs[j][0] = X0;
    *(f32x4*)&xs[j][4] = X1;
    *(f32x4*)&xs[j][8] = X2;
  }
  __syncthreads();

  float accg[4] = {0.f, 0.f, 0.f, 0.f};

  for (int jb = 0; jb < NPTS; jb += 16) {
    // ---- phase A: h1 = ReLU(LN1(x@w1^T + b1)) -> bf16 LDS (no cross-lane ops)
    #pragma unroll
    for (int sr = 0; sr < 2; ++sr) {
      const int m = sr * 8 + wid * 2 + hw;
      const int j = jb + m;
      const f32x4 X0 = *(const f32x4*)&xs[j][0];
      const f32x4 X1 = *(const f32x4*)&xs[j][4];
      const f32x4 X2 = *(const f32x4*)&xs[j][8];
      const float2 ms = *(const float2*)&st[j][0];
      s16x4 hn;
      #pragma unroll
      for (int r = 0; r < 4; ++r) {
        const float a = b1r[r]
          + X0[0] * w1r[r][0] + X0[1] * w1r[r][1] + X0[2] * w1r[r][2] + X0[3] * w1r[r][3]
          + X1[2] * w1r[r][6] + X1[3] * w1r[r][7] + X2[0] * w1r[r][8];
        const float e = (a - ms.x) * ms.y * g1r[r] + be1r[r];
        hn[r] = (short)f2bf(fmaxf(e, 0.f));
      }
      *(s16x4*)&h1s[m][h0] = hn;
    }
    __syncthreads();
    // ---- phase B: MFMA (unchanged from proven round-4 kernel)
    s16x8 af[4];
    #pragma unroll
    for (int kt = 0; kt < 4; ++kt)
      af[kt] = *(const s16x8*)&h1s[n16][kt * 32 + q16 * 8];
    f32x4 acc[4];
    #pragma unroll
    for (int dt = 0; dt < 4; ++dt) {
      f32x4 a = {0.f, 0.f, 0.f, 0.f};
      #pragma unroll
      for (int kt = 0; kt < 4; ++kt)
        a = __builtin_amdgcn_mfma_f32_16x16x32_bf16(af[kt], bfrag[dt][kt], a, 0, 0, 0);
      acc[dt] = a;
    }
    // ---- LN2 (unchanged)
    float sR[4], qR[4];
    #pragma unroll
    for (int r = 0; r < 4; ++r) {
      float s = 0.f, q = 0.f;
      #pragma unroll
      for (int dt = 0; dt < 4; ++dt) {
        const float v = acc[dt][r] + b2r[dt];
        s += v; q += v * v;
      }
      sR[r] = s; qR[r] = q;
    }
    #pragma unroll
    for (int off = 1; off < 16; off <<= 1) {
      #pragma unroll
      for (int r = 0; r < 4; ++r) {
        sR[r] += __shfl_xor(sR[r], off);
        qR[r] += __shfl_xor(qR[r], off);
      }
    }
    if (n16 == 0) {
      #pragma unroll
      for (int r = 0; r < 4; ++r) {
        red2[q16 * 4 + r][wid * 2 + 0] = sR[r];
        red2[q16 * 4 + r][wid * 2 + 1] = qR[r];
      }
    }
    __syncthreads();
    #pragma unroll
    for (int r = 0; r < 4; ++r) {
      const int row = q16 * 4 + r;
      const f32x4 p0 = *(const f32x4*)&red2[row][0];
      const f32x4 p1 = *(const f32x4*)&red2[row][4];
      const float s = p0[0] + p0[2] + p1[0] + p1[2];
      const float q = p0[1] + p0[3] + p1[1] + p1[3];
      const float mean = s * (1.f / 256.f);
      const float var = fmaxf(q * (1.f / 256.f) - mean * mean, 0.f);
      const float rs = rsqrtf(var + LN_EPS);
      #pragma unroll
      for (int dt = 0; dt < 4; ++dt) {
        const float v = acc[dt][r] + b2r[dt];
        accg[dt] += (v - mean) * rs * g2r[dt] + be2r[dt];
      }
    }
    __syncthreads();
  }
  #pragma unroll
  for (int dt = 0; dt < 4; ++dt) {
    float v = accg[dt];
    v += __shfl_xor(v, 16);
    v += __shfl_xor(v, 32);
    if (lane < 16) geo_ctx[bi * DIM + (wid * 4 + dt) * 16 + lane] = v * (1.f / 512.f);
  }
}

// ---------------- K2: per-(b,s) segment means + aggregator MLP -> comb, cnt -------------
__global__ void k2_agg(
    fpc features, const int* __restrict__ labels, const float* __restrict__ geo_ctx,
    fpc w1, fpc b1, fpc g1, fpc be1, fpc w2, fpc b2, fpc g2, fpc be2,
    float* __restrict__ comb, float* __restrict__ cntf)
{
  const int t = threadIdx.x;
  const int lane = t & 63;
  const int wid = t >> 6;
  const int b = blockIdx.x >> 6;
  const int s = blockIdx.x & 63;
  __shared__ __align__(16) int labS[NPTS];
  __shared__ __align__(16) float mfS[DIM];
  __shared__ __align__(16) float h1S[HID];
  __shared__ __align__(16) float red[8];
  for (int n = t; n < NPTS; n += 256) labS[n] = labels[b * NPTS + n];
  __syncthreads();
  float accf = 0.f, accgv = 0.f;
  int cnt = 0;
  for (int n = 0; n < NPTS; n += 4) {        // batched label reads (one b128)
    const int4 l4 = *(const int4*)&labS[n];
    if (l4.x == s) { cnt++; accf += features[(b * NPTS + n + 0) * DIM + t]; accgv += geo_ctx[(b * NPTS + n + 0) * DIM + t]; }
    if (l4.y == s) { cnt++; accf += features[(b * NPTS + n + 1) * DIM + t]; accgv += geo_ctx[(b * NPTS + n + 1) * DIM + t]; }
    if (l4.z == s) { cnt++; accf += features[(b * NPTS + n + 2) * DIM + t]; accgv += geo_ctx[(b * NPTS + n + 2) * DIM + t]; }
    if (l4.w == s) { cnt++; accf += features[(b * NPTS + n + 3) * DIM + t]; accgv += geo_ctx[(b * NPTS + n + 3) * DIM + t]; }
  }
  const float denom = fmaxf((float)cnt, 1.f);
  const float mfd = accf / denom, mgd = accgv / denom;
  mfS[t] = mfd;
  __syncthreads();
  float hval = 0.f;
  if (t < HID) {
    float o = b1[t];
    for (int k = 0; k < DIM; k += 4) {
      const f32x4 x = *(const f32x4*)&mfS[k];
      const f32x4 w = *(const f32x4*)&w1[t * DIM + k];
      o += x[0] * w[0] + x[1] * w[1] + x[2] * w[2] + x[3] * w[3];
    }
    hval = o;
  }
  float sv = (t < HID) ? hval : 0.f;
  float qv = (t < HID) ? hval * hval : 0.f;
  #pragma unroll
  for (int off = 1; off < 64; off <<= 1) { sv += __shfl_xor(sv, off); qv += __shfl_xor(qv, off); }
  if (lane == 0 && wid < 2) { red[wid * 2] = sv; red[wid * 2 + 1] = qv; }
  __syncthreads();
  if (t < HID) {
    const float s1 = red[0] + red[2], q1 = red[1] + red[3];
    const float mean = s1 * (1.f / 128.f);
    const float var = fmaxf(q1 * (1.f / 128.f) - mean * mean, 0.f);
    const float rs = rsqrtf(var + LN_EPS);
    h1S[t] = fmaxf((hval - mean) * rs * g1[t] + be1[t], 0.f);
  }
  __syncthreads();
  float o = b2[t];
  for (int k = 0; k < HID; k += 4) {
    const f32x4 x = *(const f32x4*)&h1S[k];
    const f32x4 w = *(const f32x4*)&w2[t * HID + k];
    o += x[0] * w[0] + x[1] * w[1] + x[2] * w[2] + x[3] * w[3];
  }
  float sv2 = o, qv2 = o * o;
  #pragma unroll
  for (int off = 1; off < 64; off <<= 1) { sv2 += __shfl_xor(sv2, off); qv2 += __shfl_xor(qv2, off); }
  if (lane == 0) { red[wid * 2] = sv2; red[wid * 2 + 1] = qv2; }
  __syncthreads();
  const float sa = red[0] + red[2] + red[4] + red[6];
  const float qa = red[1] + red[3] + red[5] + red[7];
  const float mean = sa * (1.f / 256.f);
  const float var = fmaxf(qa * (1.f / 256.f) - mean * mean, 0.f);
  const float rs = rsqrtf(var + LN_EPS);
  const float e = (o - mean) * rs * g2[t] + be2[t];
  comb[(b * NSEG + s) * DIM + t] = e + mgd;
  if (t == 0) cntf[b * NSEG + s] = (float)cnt;
}

// ---------------- K4: Q/K/V projections (round-4 tiling, enh fused at staging) ----------
__global__ __launch_bounds__(256) void k4_qkv(
    fpc features, const int* __restrict__ labels,
    const float* __restrict__ comb, const float* __restrict__ cntf,
    const float* __restrict__ geo_ctx,
    fpc wq, fpc bq, fpc wk, fpc bk, fpc wv, fpc bv,
    float* __restrict__ Q, float* __restrict__ Ko, float* __restrict__ V,
    float* __restrict__ enh)
{
  const int blk = blockIdx.x;
  const int proj = blk >> 6;
  const int rem = blk & 63;
  const int b = rem >> 5;
  const int nt = rem & 31;
  const int n0 = b * NPTS + nt * 16;
  fpc W = (proj == 0) ? wq : (proj == 1 ? wk : wv);
  fpc bias = (proj == 0) ? bq : (proj == 1 ? bk : bv);
  float* out = (proj == 0) ? Q : (proj == 1 ? Ko : V);
  __shared__ __align__(16) float Xs[16][256];
  const int t = threadIdx.x;
  for (int idx = t * 4; idx < 16 * 256; idx += 1024) {
    const int r = idx >> 8, c = idx & 255;
    const int row = n0 + r;
    f32x4 v;
    if (proj == 0) {
      const int l = labels[row];
      const float cn = cntf[b * NSEG + l];
      const f32x4 f = *(const f32x4*)&features[row * DIM + c];
      if (cn >= 2.f) {
        const f32x4 cb = *(const f32x4*)&comb[(b * NSEG + l) * DIM + c];
        #pragma unroll
        for (int i = 0; i < 4; ++i) v[i] = 0.7f * f[i] + 0.3f * cb[i];
      } else {
        v = f;
      }
      *(f32x4*)&enh[row * DIM + c] = v;    // exactly one proj0 block per (b,nt)
    } else {
      v = *(const f32x4*)&geo_ctx[row * DIM + c];
    }
    *(f32x4*)&Xs[r][c] = v;
  }
  __syncthreads();
  const int r0 = (t >> 6) * 4;
  const int c0 = (t & 63) * 4;
  float acc[4][4] = {};
  for (int k = 0; k < DIM; k += 4) {
    f32x4 xq[4];
    #pragma unroll
    for (int r = 0; r < 4; ++r) xq[r] = *(const f32x4*)&Xs[r0 + r][k];
    f32x4 wf[4];
    #pragma unroll
    for (int c = 0; c < 4; ++c) wf[c] = *(const f32x4*)&W[(c0 + c) * DIM + k];
    #pragma unroll
    for (int r = 0; r < 4; ++r)
      #pragma unroll
      for (int c = 0; c < 4; ++c)
        acc[r][c] += xq[r][0] * wf[c][0] + xq[r][1] * wf[c][1]
                   + xq[r][2] * wf[c][2] + xq[r][3] * wf[c][3];
  }
  #pragma unroll
  for (int r = 0; r < 4; ++r) {
    f32x4 o;
    #pragma unroll
    for (int c = 0; c < 4; ++c) o[c] = acc[r][c] + bias[c0 + c];
    *(f32x4*)&out[(n0 + r0 + r) * DIM + c0] = o;
  }
}

// ---------------- K5: attention per (b, head, 16-q-row tile) — round-4 form -------------
__global__ void k5_attn(const float* __restrict__ Q, const float* __restrict__ Kv,
                        const float* __restrict__ V, float* __restrict__ O)
{
  const int blk = blockIdx.x;
  const int qt = blk & 31;
  const int h = (blk >> 5) & 7;
  const int b = blk >> 8;
  const int t = threadIdx.x;
  __shared__ __align__(16) float Sx[16][516];
  __shared__ __align__(16) float rinv[16];
  {
    const int r = t & 15, kc = t >> 4;
    const int qrow = b * NPTS + qt * 16 + r;
    f32x4 qv[8];
    #pragma unroll
    for (int i = 0; i < 8; ++i) qv[i] = *(const f32x4*)&Q[qrow * DIM + h * 32 + i * 4];
    for (int kk = 0; kk < 32; ++kk) {
      const int krow = b * NPTS + kc * 32 + kk;
      const f32x4* kp = (const f32x4*)&Kv[krow * DIM + h * 32];
      float sd = 0.f;
      #pragma unroll
      for (int i = 0; i < 8; ++i) {
        const f32x4 kvv = kp[i];
        sd += qv[i][0] * kvv[0] + qv[i][1] * kvv[1] + qv[i][2] * kvv[2] + qv[i][3] * kvv[3];
      }
      Sx[r][kc * 32 + kk] = sd * 0.1767766952966369f;   // 1/sqrt(32)
    }
  }
  __syncthreads();
  {
    const int r2 = t >> 4, cl = t & 15;
    float mx = -3.4e38f;
    for (int i = 0; i < 32; ++i) mx = fmaxf(mx, Sx[r2][cl + 16 * i]);
    #pragma unroll
    for (int off = 1; off < 16; off <<= 1) mx = fmaxf(mx, __shfl_xor(mx, off));
    float sm = 0.f;
    for (int i = 0; i < 32; ++i) {
      const float e = __expf(Sx[r2][cl + 16 * i] - mx);
      Sx[r2][cl + 16 * i] = e;
      sm += e;
    }
    #pragma unroll
    for (int off = 1; off < 16; off <<= 1) sm += __shfl_xor(sm, off);
    if (cl == 0) rinv[r2] = 1.f / sm;
  }
  __syncthreads();
  {
    const int r3 = t >> 4;
    const int e0 = (t & 15) * 2;
    float o0 = 0.f, o1 = 0.f;
    for (int k = 0; k < NPTS; ++k) {
      const float p = Sx[r3][k];
      const float2 vv = *(const float2*)&V[(b * NPTS + k) * DIM + h * 32 + e0];
      o0 += p * vv.x; o1 += p * vv.y;
    }
    const float ri = rinv[r3];
    float2 ov; ov.x = o0 * ri; ov.y = o1 * ri;
    *(float2*)&O[(b * NPTS + qt * 16 + r3) * DIM + h * 32 + e0] = ov;
  }
}

// ---------------- K6: out = enh + 0.5*(O @ wo^T + bo) — round-4 form --------------------
__global__ void k6_out(const float* __restrict__ O, const float* __restrict__ enh,
                       fpc wo, fpc bo, float* __restrict__ out)
{
  const int blk = blockIdx.x;          // b*64 + 8-row tile
  const int b = blk >> 6;
  const int nt = blk & 63;
  const int n0 = b * NPTS + nt * 8;
  const int t = threadIdx.x;
  __shared__ __align__(16) float Xs[8][256];
  for (int idx = t * 4; idx < 8 * 256; idx += 1024) {
    const int r = idx >> 8, c = idx & 255;
    *(f32x4*)&Xs[r][c] = *(const f32x4*)&O[(n0 + r) * DIM + c];
  }
  __syncthreads();
  const int r0 = (t >> 6) * 2;
  const int c0 = (t & 63) * 4;
  float acc[2][4] = {};
  for (int k = 0; k < DIM; k += 4) {
    f32x4 xq[2];
    xq[0] = *(const f32x4*)&Xs[r0][k];
    xq[1] = *(const f32x4*)&Xs[r0 + 1][k];
    #pragma unroll
    for (int c = 0; c < 4; ++c) {
      const f32x4 w = *(const f32x4*)&wo[(c0 + c) * DIM + k];
      #pragma unroll
      for (int r = 0; r < 2; ++r)
        acc[r][c] += xq[r][0] * w[0] + xq[r][1] * w[1] + xq[r][2] * w[2] + xq[r][3] * w[3];
    }
  }
  #pragma unroll
  for (int r = 0; r < 2; ++r) {
    const int row = n0 + r0 + r;
    const f32x4 ev = *(const f32x4*)&enh[row * DIM + c0];
    f32x4 o;
    #pragma unroll
    for (int c = 0; c < 4; ++c)
      o[c] = ev[c] + 0.5f * (acc[r][c] + bo[c0 + c]);
    *(f32x4*)&out[row * DIM + c0] = o;
  }
}

extern "C" void kernel_launch(void* const* d_in, const int* in_sizes, int n_in,
                              void* d_out, int out_size, void* d_ws, size_t ws_size,
                              hipStream_t stream)
{
  fpc coords  = (fpc)d_in[0];
  fpc features= (fpc)d_in[1];
  const int* labels = (const int*)d_in[2];
  fpc ge_w1 = (fpc)d_in[3],  ge_b1 = (fpc)d_in[4],  ge_g1 = (fpc)d_in[5],  ge_be1 = (fpc)d_in[6];
  fpc ge_w2 = (fpc)d_in[7],  ge_b2 = (fpc)d_in[8],  ge_g2 = (fpc)d_in[9],  ge_be2 = (fpc)d_in[10];
  fpc ag_w1 = (fpc)d_in[11], ag_b1 = (fpc)d_in[12], ag_g1 = (fpc)d_in[13], ag_be1 = (fpc)d_in[14];
  fpc ag_w2 = (fpc)d_in[15], ag_b2 = (fpc)d_in[16], ag_g2 = (fpc)d_in[17], ag_be2 = (fpc)d_in[18];
  fpc wq = (fpc)d_in[19], bq = (fpc)d_in[20];
  fpc wk = (fpc)d_in[21], bk = (fpc)d_in[22];
  fpc wv = (fpc)d_in[23], bv = (fpc)d_in[24];
  fpc wo = (fpc)d_in[25], bo = (fpc)d_in[26];

  float* ws = (float*)d_ws;
  float* geo_ctx = ws;                    // 262144
  float* comb    = geo_ctx + 262144;      // 32768
  float* cntf    = comb + 32768;          // 128
  float* enh     = cntf + 128;            // 262144
  float* Qb      = enh + 262144;          // 262144
  float* Kb      = Qb + 262144;           // 262144
  float* Vb      = Kb + 262144;           // 262144
  float* Ob      = Vb + 262144;           // 262144

  k1_geo<<<1024, 256, 0, stream>>>(coords, ge_w1, ge_b1, ge_g1, ge_be1,
                                   ge_w2, ge_b2, ge_g2, ge_be2, geo_ctx);
  k2_agg<<<128, 256, 0, stream>>>(features, labels, geo_ctx,
                                  ag_w1, ag_b1, ag_g1, ag_be1,
                                  ag_w2, ag_b2, ag_g2, ag_be2, comb, cntf);
  k4_qkv<<<192, 256, 0, stream>>>(features, labels, comb, cntf, geo_ctx,
                                  wq, bq, wk, bk, wv, bv, Qb, Kb, Vb, enh);
  k5_attn<<<512, 256, 0, stream>>>(Qb, Kb, Vb, Ob);
  k6_out<<<128, 256, 0, stream>>>(Ob, enh, wo, bo, (float*)d_out);
}

// Round 8
// 407.804 us; speedup vs baseline: 1.3828x; 1.0184x over previous
//
#include <hip/hip_runtime.h>

#define NPTS 512
#define DIM  256
#define HID  128
#define NSEG 64
#define LN_EPS 1e-5f

typedef short s16x4 __attribute__((ext_vector_type(4)));
typedef short s16x8 __attribute__((ext_vector_type(8)));
typedef float f32x4 __attribute__((ext_vector_type(4)));
typedef const float* fpc;

__device__ __forceinline__ unsigned short f2bf(float f) {
  unsigned int u = __builtin_bit_cast(unsigned int, f);
  u += 0x7FFFu + ((u >> 16) & 1u);
  return (unsigned short)(u >> 16);
}

// ---------------- K1 v3: 32-j tiles (halved barrier count vs v2b) -----------------------
// Startup precomputes x[9] + LN1 stats (w1-quadform) for all 512 j into LDS; phase A is
// pure FMA. Per 32-j iteration: 2 MFMA tile-chains + 2 independent LN2 reductions between
// 3 barriers (v2b had 3 barriers per 16 j). launch_bounds (256,2): R6 showed (256,4)
// spills bfrag to scratch (918 MB fetch). Keep (256,2).
__global__ __launch_bounds__(256, 2) void k1_geo(
    fpc coords, fpc w1, fpc b1, fpc g1, fpc be1,
    fpc w2, fpc b2, fpc g2, fpc be2,
    float* __restrict__ geo_ctx)
{
  const int t = threadIdx.x;
  const int lane = t & 63;
  const int wid = t >> 6;
  const int bi = blockIdx.x;           // b*512 + i
  const int b = bi >> 9;

  __shared__ __align__(16) float xs[NPTS][12];           // 24KB  x features (x4,x5 = 0)
  __shared__ __align__(16) float st[NPTS][2];            // 4KB   {mean, rstd} of LN1 pre-act
  __shared__ __align__(16) float qf[128];                // Q[9][12] @0, cw@108, tv@117, cb@126, sb2@127
  __shared__ __align__(16) unsigned short h1s[32][136];  // 8.5KB
  __shared__ __align__(16) float red2[32][8];            // 1KB

  // ---- startup A: quadform constants from w1/b1 (cooperative)
  if (t < 101) {
    float acc = 0.f;
    if (t < 81) {
      const int a = t / 9, c = t % 9;
      for (int h = 0; h < HID; ++h) acc += w1[h * 9 + a] * w1[h * 9 + c];
      qf[a * 12 + c] = acc;
    } else if (t < 90) {
      const int a = t - 81;
      for (int h = 0; h < HID; ++h) acc += w1[h * 9 + a];
      qf[108 + a] = acc;
    } else if (t < 99) {
      const int a = t - 90;
      for (int h = 0; h < HID; ++h) acc += b1[h] * w1[h * 9 + a];
      qf[117 + a] = acc;
    } else if (t == 99) {
      for (int h = 0; h < HID; ++h) acc += b1[h];
      qf[126] = acc;
    } else {
      for (int h = 0; h < HID; ++h) acc += b1[h] * b1[h];
      qf[127] = acc;
    }
  }
  // ---- per-thread weight registers (phase A channels)
  const int u  = lane & 31;
  const int hw = lane >> 5;
  const int h0 = u * 4;
  float w1r[4][9], b1r[4], g1r[4], be1r[4];
  #pragma unroll
  for (int r = 0; r < 4; ++r) {
    #pragma unroll
    for (int k = 0; k < 9; ++k) w1r[r][k] = w1[(h0 + r) * 9 + k];
    b1r[r] = b1[h0 + r]; g1r[r] = g1[h0 + r]; be1r[r] = be1[h0 + r];
  }
  const int n16 = lane & 15;
  const int q16 = lane >> 4;
  s16x8 bfrag[4][4];
  float b2r[4], g2r[4], be2r[4];
  #pragma unroll
  for (int dt = 0; dt < 4; ++dt) {
    const int d = (wid * 4 + dt) * 16 + n16;
    b2r[dt] = b2[d]; g2r[dt] = g2[d]; be2r[dt] = be2[d];
    #pragma unroll
    for (int kt = 0; kt < 4; ++kt) {
      const int kb = kt * 32 + q16 * 8;
      s16x8 f;
      #pragma unroll
      for (int jj = 0; jj < 8; ++jj) f[jj] = (short)f2bf(w2[d * HID + kb + jj]);
      bfrag[dt][kt] = f;
    }
  }
  const float cix = coords[bi * 3 + 0];
  const float ciy = coords[bi * 3 + 1];
  const float ciz = coords[bi * 3 + 2];
  __syncthreads();

  // ---- startup B: x + LN1 stats for all 512 j (2 per thread)
  #pragma unroll
  for (int jj = 0; jj < 2; ++jj) {
    const int j = t + jj * 256;
    const float cjx = coords[(b * NPTS + j) * 3 + 0];
    const float cjy = coords[(b * NPTS + j) * 3 + 1];
    const float cjz = coords[(b * NPTS + j) * 3 + 2];
    const float rx = cix - cjx, ry = ciy - cjy, rz = ciz - cjz;
    const float dist = sqrtf(rx * rx + ry * ry + rz * rz);
    const float inv = 1.f / fmaxf(dist, 1e-12f);
    const float r0 = rx * inv, r1 = ry * inv, r2 = rz * inv;
    const float x0 = dist, x1 = r0, x2 = r1, x3 = r2;
    const float x6 = r1 * r2, x7 = r0 * r1, x8 = r0 * r2;
    float S1 = qf[126] + qf[108] * x0 + qf[109] * x1 + qf[110] * x2 + qf[111] * x3
             + qf[114] * x6 + qf[115] * x7 + qf[116] * x8;
    float tx = qf[117] * x0 + qf[118] * x1 + qf[119] * x2 + qf[120] * x3
             + qf[123] * x6 + qf[124] * x7 + qf[125] * x8;
    const float xv[9] = {x0, x1, x2, x3, 0.f, 0.f, x6, x7, x8};
    float quad = 0.f;
    #pragma unroll
    for (int a = 0; a < 9; ++a) {
      if (a == 4 || a == 5) continue;
      const f32x4 q0 = *(const f32x4*)&qf[a * 12];
      const f32x4 q1 = *(const f32x4*)&qf[a * 12 + 4];
      const f32x4 q2 = *(const f32x4*)&qf[a * 12 + 8];
      const float ya = q0[0] * x0 + q0[1] * x1 + q0[2] * x2 + q0[3] * x3
                     + q1[2] * x6 + q1[3] * x7 + q2[0] * x8;
      quad += ya * xv[a];
    }
    const float S2 = quad + 2.f * tx + qf[127];
    const float mean = S1 * (1.f / 128.f);
    const float var = fmaxf(S2 * (1.f / 128.f) - mean * mean, 0.f);
    st[j][0] = mean;
    st[j][1] = rsqrtf(var + LN_EPS);
    f32x4 X0; X0[0] = x0; X0[1] = x1; X0[2] = x2; X0[3] = x3;
    f32x4 X1; X1[0] = 0.f; X1[1] = 0.f; X1[2] = x6; X1[3] = x7;
    f32x4 X2; X2[0] = x8; X2[1] = 0.f; X2[2] = 0.f; X2[3] = 0.f;
    *(f32x4*)&xs[j][0] = X0;
    *(f32x4*)&xs[j][4] = X1;
    *(f32x4*)&xs[j][8] = X2;
  }
  __syncthreads();

  float accg[4] = {0.f, 0.f, 0.f, 0.f};

  for (int jb = 0; jb < NPTS; jb += 32) {
    // ---- phase A: 32 rows of h1 = ReLU(LN1(x@w1^T + b1)) -> bf16 LDS
    #pragma unroll
    for (int sr = 0; sr < 4; ++sr) {
      const int m = sr * 8 + wid * 2 + hw;       // 0..31
      const int j = jb + m;
      const f32x4 X0 = *(const f32x4*)&xs[j][0];
      const f32x4 X1 = *(const f32x4*)&xs[j][4];
      const f32x4 X2 = *(const f32x4*)&xs[j][8];
      const float2 ms = *(const float2*)&st[j][0];
      s16x4 hn;
      #pragma unroll
      for (int r = 0; r < 4; ++r) {
        const float a = b1r[r]
          + X0[0] * w1r[r][0] + X0[1] * w1r[r][1] + X0[2] * w1r[r][2] + X0[3] * w1r[r][3]
          + X1[2] * w1r[r][6] + X1[3] * w1r[r][7] + X2[0] * w1r[r][8];
        const float e = (a - ms.x) * ms.y * g1r[r] + be1r[r];
        hn[r] = (short)f2bf(fmaxf(e, 0.f));
      }
      *(s16x4*)&h1s[m][h0] = hn;
    }
    __syncthreads();
    // ---- phase B: 2 MFMA tile-chains (rows 0-15, 16-31)
    f32x4 acc2[2][4];
    #pragma unroll
    for (int mt = 0; mt < 2; ++mt) {
      s16x8 af[4];
      #pragma unroll
      for (int kt = 0; kt < 4; ++kt)
        af[kt] = *(const s16x8*)&h1s[mt * 16 + n16][kt * 32 + q16 * 8];
      #pragma unroll
      for (int dt = 0; dt < 4; ++dt) {
        f32x4 a = {0.f, 0.f, 0.f, 0.f};
        #pragma unroll
        for (int kt = 0; kt < 4; ++kt)
          a = __builtin_amdgcn_mfma_f32_16x16x32_bf16(af[kt], bfrag[dt][kt], a, 0, 0, 0);
        acc2[mt][dt] = a;
      }
    }
    // ---- LN2 partials: 2 independent shuffle trees
    float sR[2][4], qR[2][4];
    #pragma unroll
    for (int mt = 0; mt < 2; ++mt)
      #pragma unroll
      for (int r = 0; r < 4; ++r) {
        float s = 0.f, q = 0.f;
        #pragma unroll
        for (int dt = 0; dt < 4; ++dt) {
          const float v = acc2[mt][dt][r] + b2r[dt];
          s += v; q += v * v;
        }
        sR[mt][r] = s; qR[mt][r] = q;
      }
    #pragma unroll
    for (int off = 1; off < 16; off <<= 1) {
      #pragma unroll
      for (int mt = 0; mt < 2; ++mt)
        #pragma unroll
        for (int r = 0; r < 4; ++r) {
          sR[mt][r] += __shfl_xor(sR[mt][r], off);
          qR[mt][r] += __shfl_xor(qR[mt][r], off);
        }
    }
    if (n16 == 0) {
      #pragma unroll
      for (int mt = 0; mt < 2; ++mt)
        #pragma unroll
        for (int r = 0; r < 4; ++r) {
          red2[mt * 16 + q16 * 4 + r][wid * 2 + 0] = sR[mt][r];
          red2[mt * 16 + q16 * 4 + r][wid * 2 + 1] = qR[mt][r];
        }
    }
    __syncthreads();
    #pragma unroll
    for (int mt = 0; mt < 2; ++mt)
      #pragma unroll
      for (int r = 0; r < 4; ++r) {
        const int row = mt * 16 + q16 * 4 + r;
        const f32x4 p0 = *(const f32x4*)&red2[row][0];
        const f32x4 p1 = *(const f32x4*)&red2[row][4];
        const float s = p0[0] + p0[2] + p1[0] + p1[2];
        const float q = p0[1] + p0[3] + p1[1] + p1[3];
        const float mean = s * (1.f / 256.f);
        const float var = fmaxf(q * (1.f / 256.f) - mean * mean, 0.f);
        const float rs = rsqrtf(var + LN_EPS);
        #pragma unroll
        for (int dt = 0; dt < 4; ++dt) {
          const float v = acc2[mt][dt][r] + b2r[dt];
          accg[dt] += (v - mean) * rs * g2r[dt] + be2r[dt];
        }
      }
    __syncthreads();
  }
  #pragma unroll
  for (int dt = 0; dt < 4; ++dt) {
    float v = accg[dt];
    v += __shfl_xor(v, 16);
    v += __shfl_xor(v, 32);
    if (lane < 16) geo_ctx[bi * DIM + (wid * 4 + dt) * 16 + lane] = v * (1.f / 512.f);
  }
}

// ---------------- K2: per-(b,s) segment means + aggregator MLP -> comb, cnt -------------
__global__ void k2_agg(
    fpc features, const int* __restrict__ labels, const float* __restrict__ geo_ctx,
    fpc w1, fpc b1, fpc g1, fpc be1, fpc w2, fpc b2, fpc g2, fpc be2,
    float* __restrict__ comb, float* __restrict__ cntf)
{
  const int t = threadIdx.x;
  const int lane = t & 63;
  const int wid = t >> 6;
  const int b = blockIdx.x >> 6;
  const int s = blockIdx.x & 63;
  __shared__ __align__(16) int labS[NPTS];
  __shared__ __align__(16) float mfS[DIM];
  __shared__ __align__(16) float h1S[HID];
  __shared__ __align__(16) float red[8];
  for (int n = t; n < NPTS; n += 256) labS[n] = labels[b * NPTS + n];
  __syncthreads();
  float accf = 0.f, accgv = 0.f;
  int cnt = 0;
  for (int n = 0; n < NPTS; n += 4) {
    const int4 l4 = *(const int4*)&labS[n];
    if (l4.x == s) { cnt++; accf += features[(b * NPTS + n + 0) * DIM + t]; accgv += geo_ctx[(b * NPTS + n + 0) * DIM + t]; }
    if (l4.y == s) { cnt++; accf += features[(b * NPTS + n + 1) * DIM + t]; accgv += geo_ctx[(b * NPTS + n + 1) * DIM + t]; }
    if (l4.z == s) { cnt++; accf += features[(b * NPTS + n + 2) * DIM + t]; accgv += geo_ctx[(b * NPTS + n + 2) * DIM + t]; }
    if (l4.w == s) { cnt++; accf += features[(b * NPTS + n + 3) * DIM + t]; accgv += geo_ctx[(b * NPTS + n + 3) * DIM + t]; }
  }
  const float denom = fmaxf((float)cnt, 1.f);
  const float mfd = accf / denom, mgd = accgv / denom;
  mfS[t] = mfd;
  __syncthreads();
  float hval = 0.f;
  if (t < HID) {
    float o = b1[t];
    for (int k = 0; k < DIM; k += 4) {
      const f32x4 x = *(const f32x4*)&mfS[k];
      const f32x4 w = *(const f32x4*)&w1[t * DIM + k];
      o += x[0] * w[0] + x[1] * w[1] + x[2] * w[2] + x[3] * w[3];
    }
    hval = o;
  }
  float sv = (t < HID) ? hval : 0.f;
  float qv = (t < HID) ? hval * hval : 0.f;
  #pragma unroll
  for (int off = 1; off < 64; off <<= 1) { sv += __shfl_xor(sv, off); qv += __shfl_xor(qv, off); }
  if (lane == 0 && wid < 2) { red[wid * 2] = sv; red[wid * 2 + 1] = qv; }
  __syncthreads();
  if (t < HID) {
    const float s1 = red[0] + red[2], q1 = red[1] + red[3];
    const float mean = s1 * (1.f / 128.f);
    const float var = fmaxf(q1 * (1.f / 128.f) - mean * mean, 0.f);
    const float rs = rsqrtf(var + LN_EPS);
    h1S[t] = fmaxf((hval - mean) * rs * g1[t] + be1[t], 0.f);
  }
  __syncthreads();
  float o = b2[t];
  for (int k = 0; k < HID; k += 4) {
    const f32x4 x = *(const f32x4*)&h1S[k];
    const f32x4 w = *(const f32x4*)&w2[t * HID + k];
    o += x[0] * w[0] + x[1] * w[1] + x[2] * w[2] + x[3] * w[3];
  }
  float sv2 = o, qv2 = o * o;
  #pragma unroll
  for (int off = 1; off < 64; off <<= 1) { sv2 += __shfl_xor(sv2, off); qv2 += __shfl_xor(qv2, off); }
  if (lane == 0) { red[wid * 2] = sv2; red[wid * 2 + 1] = qv2; }
  __syncthreads();
  const float sa = red[0] + red[2] + red[4] + red[6];
  const float qa = red[1] + red[3] + red[5] + red[7];
  const float mean = sa * (1.f / 256.f);
  const float var = fmaxf(qa * (1.f / 256.f) - mean * mean, 0.f);
  const float rs = rsqrtf(var + LN_EPS);
  const float e = (o - mean) * rs * g2[t] + be2[t];
  comb[(b * NSEG + s) * DIM + t] = e + mgd;
  if (t == 0) cntf[b * NSEG + s] = (float)cnt;
}

// ---------------- K4: Q/K/V projections (round-4 tiling, enh fused at staging) ----------
__global__ __launch_bounds__(256) void k4_qkv(
    fpc features, const int* __restrict__ labels,
    const float* __restrict__ comb, const float* __restrict__ cntf,
    const float* __restrict__ geo_ctx,
    fpc wq, fpc bq, fpc wk, fpc bk, fpc wv, fpc bv,
    float* __restrict__ Q, float* __restrict__ Ko, float* __restrict__ V,
    float* __restrict__ enh)
{
  const int blk = blockIdx.x;
  const int proj = blk >> 6;
  const int rem = blk & 63;
  const int b = rem >> 5;
  const int nt = rem & 31;
  const int n0 = b * NPTS + nt * 16;
  fpc W = (proj == 0) ? wq : (proj == 1 ? wk : wv);
  fpc bias = (proj == 0) ? bq : (proj == 1 ? bk : bv);
  float* out = (proj == 0) ? Q : (proj == 1 ? Ko : V);
  __shared__ __align__(16) float Xs[16][256];
  const int t = threadIdx.x;
  for (int idx = t * 4; idx < 16 * 256; idx += 1024) {
    const int r = idx >> 8, c = idx & 255;
    const int row = n0 + r;
    f32x4 v;
    if (proj == 0) {
      const int l = labels[row];
      const float cn = cntf[b * NSEG + l];
      const f32x4 f = *(const f32x4*)&features[row * DIM + c];
      if (cn >= 2.f) {
        const f32x4 cb = *(const f32x4*)&comb[(b * NSEG + l) * DIM + c];
        #pragma unroll
        for (int i = 0; i < 4; ++i) v[i] = 0.7f * f[i] + 0.3f * cb[i];
      } else {
        v = f;
      }
      *(f32x4*)&enh[row * DIM + c] = v;
    } else {
      v = *(const f32x4*)&geo_ctx[row * DIM + c];
    }
    *(f32x4*)&Xs[r][c] = v;
  }
  __syncthreads();
  const int r0 = (t >> 6) * 4;
  const int c0 = (t & 63) * 4;
  float acc[4][4] = {};
  for (int k = 0; k < DIM; k += 4) {
    f32x4 xq[4];
    #pragma unroll
    for (int r = 0; r < 4; ++r) xq[r] = *(const f32x4*)&Xs[r0 + r][k];
    f32x4 wf[4];
    #pragma unroll
    for (int c = 0; c < 4; ++c) wf[c] = *(const f32x4*)&W[(c0 + c) * DIM + k];
    #pragma unroll
    for (int r = 0; r < 4; ++r)
      #pragma unroll
      for (int c = 0; c < 4; ++c)
        acc[r][c] += xq[r][0] * wf[c][0] + xq[r][1] * wf[c][1]
                   + xq[r][2] * wf[c][2] + xq[r][3] * wf[c][3];
  }
  #pragma unroll
  for (int r = 0; r < 4; ++r) {
    f32x4 o;
    #pragma unroll
    for (int c = 0; c < 4; ++c) o[c] = acc[r][c] + bias[c0 + c];
    *(f32x4*)&out[(n0 + r0 + r) * DIM + c0] = o;
  }
}

// ---------------- K5: attention per (b, head, 16-q-row tile) — round-4 form -------------
__global__ void k5_attn(const float* __restrict__ Q, const float* __restrict__ Kv,
                        const float* __restrict__ V, float* __restrict__ O)
{
  const int blk = blockIdx.x;
  const int qt = blk & 31;
  const int h = (blk >> 5) & 7;
  const int b = blk >> 8;
  const int t = threadIdx.x;
  __shared__ __align__(16) float Sx[16][516];
  __shared__ __align__(16) float rinv[16];
  {
    const int r = t & 15, kc = t >> 4;
    const int qrow = b * NPTS + qt * 16 + r;
    f32x4 qv[8];
    #pragma unroll
    for (int i = 0; i < 8; ++i) qv[i] = *(const f32x4*)&Q[qrow * DIM + h * 32 + i * 4];
    for (int kk = 0; kk < 32; ++kk) {
      const int krow = b * NPTS + kc * 32 + kk;
      const f32x4* kp = (const f32x4*)&Kv[krow * DIM + h * 32];
      float sd = 0.f;
      #pragma unroll
      for (int i = 0; i < 8; ++i) {
        const f32x4 kvv = kp[i];
        sd += qv[i][0] * kvv[0] + qv[i][1] * kvv[1] + qv[i][2] * kvv[2] + qv[i][3] * kvv[3];
      }
      Sx[r][kc * 32 + kk] = sd * 0.1767766952966369f;   // 1/sqrt(32)
    }
  }
  __syncthreads();
  {
    const int r2 = t >> 4, cl = t & 15;
    float mx = -3.4e38f;
    for (int i = 0; i < 32; ++i) mx = fmaxf(mx, Sx[r2][cl + 16 * i]);
    #pragma unroll
    for (int off = 1; off < 16; off <<= 1) mx = fmaxf(mx, __shfl_xor(mx, off));
    float sm = 0.f;
    for (int i = 0; i < 32; ++i) {
      const float e = __expf(Sx[r2][cl + 16 * i] - mx);
      Sx[r2][cl + 16 * i] = e;
      sm += e;
    }
    #pragma unroll
    for (int off = 1; off < 16; off <<= 1) sm += __shfl_xor(sm, off);
    if (cl == 0) rinv[r2] = 1.f / sm;
  }
  __syncthreads();
  {
    const int r3 = t >> 4;
    const int e0 = (t & 15) * 2;
    float o0 = 0.f, o1 = 0.f;
    for (int k = 0; k < NPTS; ++k) {
      const float p = Sx[r3][k];
      const float2 vv = *(const float2*)&V[(b * NPTS + k) * DIM + h * 32 + e0];
      o0 += p * vv.x; o1 += p * vv.y;
    }
    const float ri = rinv[r3];
    float2 ov; ov.x = o0 * ri; ov.y = o1 * ri;
    *(float2*)&O[(b * NPTS + qt * 16 + r3) * DIM + h * 32 + e0] = ov;
  }
}

// ---------------- K6: out = enh + 0.5*(O @ wo^T + bo) — round-4 form --------------------
__global__ void k6_out(const float* __restrict__ O, const float* __restrict__ enh,
                       fpc wo, fpc bo, float* __restrict__ out)
{
  const int blk = blockIdx.x;          // b*64 + 8-row tile
  const int b = blk >> 6;
  const int nt = blk & 63;
  const int n0 = b * NPTS + nt * 8;
  const int t = threadIdx.x;
  __shared__ __align__(16) float Xs[8][256];
  for (int idx = t * 4; idx < 8 * 256; idx += 1024) {
    const int r = idx >> 8, c = idx & 255;
    *(f32x4*)&Xs[r][c] = *(const f32x4*)&O[(n0 + r) * DIM + c];
  }
  __syncthreads();
  const int r0 = (t >> 6) * 2;
  const int c0 = (t & 63) * 4;
  float acc[2][4] = {};
  for (int k = 0; k < DIM; k += 4) {
    f32x4 xq[2];
    xq[0] = *(const f32x4*)&Xs[r0][k];
    xq[1] = *(const f32x4*)&Xs[r0 + 1][k];
    #pragma unroll
    for (int c = 0; c < 4; ++c) {
      const f32x4 w = *(const f32x4*)&wo[(c0 + c) * DIM + k];
      #pragma unroll
      for (int r = 0; r < 2; ++r)
        acc[r][c] += xq[r][0] * w[0] + xq[r][1] * w[1] + xq[r][2] * w[2] + xq[r][3] * w[3];
    }
  }
  #pragma unroll
  for (int r = 0; r < 2; ++r) {
    const int row = n0 + r0 + r;
    const f32x4 ev = *(const f32x4*)&enh[row * DIM + c0];
    f32x4 o;
    #pragma unroll
    for (int c = 0; c < 4; ++c)
      o[c] = ev[c] + 0.5f * (acc[r][c] + bo[c0 + c]);
    *(f32x4*)&out[row * DIM + c0] = o;
  }
}

extern "C" void kernel_launch(void* const* d_in, const int* in_sizes, int n_in,
                              void* d_out, int out_size, void* d_ws, size_t ws_size,
                              hipStream_t stream)
{
  fpc coords  = (fpc)d_in[0];
  fpc features= (fpc)d_in[1];
  const int* labels = (const int*)d_in[2];
  fpc ge_w1 = (fpc)d_in[3],  ge_b1 = (fpc)d_in[4],  ge_g1 = (fpc)d_in[5],  ge_be1 = (fpc)d_in[6];
  fpc ge_w2 = (fpc)d_in[7],  ge_b2 = (fpc)d_in[8],  ge_g2 = (fpc)d_in[9],  ge_be2 = (fpc)d_in[10];
  fpc ag_w1 = (fpc)d_in[11], ag_b1 = (fpc)d_in[12], ag_g1 = (fpc)d_in[13], ag_be1 = (fpc)d_in[14];
  fpc ag_w2 = (fpc)d_in[15], ag_b2 = (fpc)d_in[16], ag_g2 = (fpc)d_in[17], ag_be2 = (fpc)d_in[18];
  fpc wq = (fpc)d_in[19], bq = (fpc)d_in[20];
  fpc wk = (fpc)d_in[21], bk = (fpc)d_in[22];
  fpc wv = (fpc)d_in[23], bv = (fpc)d_in[24];
  fpc wo = (fpc)d_in[25], bo = (fpc)d_in[26];

  float* ws = (float*)d_ws;
  float* geo_ctx = ws;                    // 262144
  float* comb    = geo_ctx + 262144;      // 32768
  float* cntf    = comb + 32768;          // 128
  float* enh     = cntf + 128;            // 262144
  float* Qb      = enh + 262144;          // 262144
  float* Kb      = Qb + 262144;           // 262144
  float* Vb      = Kb + 262144;           // 262144
  float* Ob      = Vb + 262144;           // 262144

  k1_geo<<<1024, 256, 0, stream>>>(coords, ge_w1, ge_b1, ge_g1, ge_be1,
                                   ge_w2, ge_b2, ge_g2, ge_be2, geo_ctx);
  k2_agg<<<128, 256, 0, stream>>>(features, labels, geo_ctx,
                                  ag_w1, ag_b1, ag_g1, ag_be1,
                                  ag_w2, ag_b2, ag_g2, ag_be2, comb, cntf);
  k4_qkv<<<192, 256, 0, stream>>>(features, labels, comb, cntf, geo_ctx,
                                  wq, bq, wk, bk, wv, bv, Qb, Kb, Vb, enh);
  k5_attn<<<512, 256, 0, stream>>>(Qb, Kb, Vb, Ob);
  k6_out<<<128, 256, 0, stream>>>(Ob, enh, wo, bo, (float*)d_out);
}